// Round 13
// baseline (176.798 us; speedup 1.0000x reference)
//
#include <hip/hip_runtime.h>

typedef _Float16 f16;
typedef _Float16 f16x4 __attribute__((ext_vector_type(4)));
typedef _Float16 f16x8 __attribute__((ext_vector_type(8)));
typedef float f32x4 __attribute__((ext_vector_type(4)));

#define N_NODES 50000
#define N_EDGES 800000
#define N_CLASSES 10
#define CAP 64           // per-node bucket capacity; deg~Poisson(16), P(>=64)~e^-128
#define EB4 ((N_EDGES + 1023) / 1024)   // 782 edge blocks, 4 edges/thread
#define XB  ((N_NODES * 128 / 8) / 256) // 3125 convert blocks

// ---------------------------------------------------------------------------
// Zero the degree counters (~2us; rocclr fillBuffer was ~40us)
// ---------------------------------------------------------------------------
__global__ void zero_cnt_kernel(int* __restrict__ cnt) {
    int i = blockIdx.x * 256 + threadIdx.x;
    if (i < N_NODES / 4) ((int4*)cnt)[i] = make_int4(0, 0, 0, 0);
}

// ---------------------------------------------------------------------------
// Fused build. Edge blocks: 4 edges/thread -> 4 independent atomic chains in
// flight per lane (ILP over the ~600cy atomic round-trip). Convert blocks:
// x f32->f16. Tail blocks: weight packing.
// ---------------------------------------------------------------------------
__global__ void build_fused_kernel(const int* __restrict__ src, const int* __restrict__ dst,
                                   int* __restrict__ cnt, unsigned short* __restrict__ bucket,
                                   const float* __restrict__ x,
                                   const float* __restrict__ w1l, const float* __restrict__ w1r,
                                   const float* __restrict__ w2l, const float* __restrict__ w2r,
                                   f16* __restrict__ xh, f16* __restrict__ W1, f16* __restrict__ W2cat) {
    int bid = blockIdx.x;
    if (bid < EB4) {
        int e0 = bid * 1024 + threadIdx.x;
#pragma unroll
        for (int q = 0; q < 4; q++) {
            int e = e0 + q * 256;
            if (e < N_EDGES) {
                int d = dst[e];
                int s = atomicAdd(&cnt[d], 1);
                if (s < CAP) bucket[(long long)d * CAP + s] = (unsigned short)src[e];
            }
        }
    } else if (bid < EB4 + XB) {
        long long base = ((long long)(bid - EB4) * 256 + threadIdx.x) * 8;
        float4 a = *(const float4*)(x + base);
        float4 b = *(const float4*)(x + base + 4);
        f16x8 o;
        o[0] = (f16)a.x; o[1] = (f16)a.y; o[2] = (f16)a.z; o[3] = (f16)a.w;
        o[4] = (f16)b.x; o[5] = (f16)b.y; o[6] = (f16)b.z; o[7] = (f16)b.w;
        *(f16x8*)(xh + base) = o;
    } else {
        int wt = (bid - EB4 - XB) * 256 + threadIdx.x;   // 0..1023
        for (int idx = wt; idx < 128 * 256; idx += 1024) {
            int n = idx >> 8, k = idx & 255;
            W1[idx] = (f16)(k < 128 ? w1l[n * 128 + k] : w1r[n * 128 + k - 128]);
        }
        for (int idx = wt; idx < 128 * 128; idx += 1024) {
            int n = idx >> 7, k = idx & 127;
            W2cat[idx] = (f16)(n < 64 ? w2l[n * 128 + k] : w2r[(n - 64) * 128 + k]);
        }
    }
}

// ---------------------------------------------------------------------------
// Layer-1 aggregation: 2 nodes/wave, 32 lanes x f16x4 (8B) per row (256B).
// ---------------------------------------------------------------------------
__global__ void agg_mean_f16_kernel(const f16* __restrict__ feat,
                                    const int* __restrict__ cnt,
                                    const unsigned short* __restrict__ bucket,
                                    f16* __restrict__ outb) {
    int node = blockIdx.x * 8 + (threadIdx.x >> 5);
    int l  = threadIdx.x & 31;
    int bl = threadIdx.x & 32;
    int deg = cnt[node];
    int n_it = deg < CAP ? deg : CAP;
    const unsigned short* b = bucket + (long long)node * CAP;
    int my0 = (l < n_it)      ? (int)b[l]      : 0;
    int my1 = (32 + l < n_it) ? (int)b[32 + l] : 0;
    const f16x4* f4 = (const f16x4*)feat;
    float a0 = 0.f, a1 = 0.f, a2 = 0.f, a3 = 0.f;
    int j = 0;
    int lim0 = n_it < 32 ? n_it : 32;
    for (; j + 8 <= lim0; j += 8) {
        f16x4 v0 = f4[(long long)__shfl(my0, bl + j + 0) * 32 + l];
        f16x4 v1 = f4[(long long)__shfl(my0, bl + j + 1) * 32 + l];
        f16x4 v2 = f4[(long long)__shfl(my0, bl + j + 2) * 32 + l];
        f16x4 v3 = f4[(long long)__shfl(my0, bl + j + 3) * 32 + l];
        f16x4 v4 = f4[(long long)__shfl(my0, bl + j + 4) * 32 + l];
        f16x4 v5 = f4[(long long)__shfl(my0, bl + j + 5) * 32 + l];
        f16x4 v6 = f4[(long long)__shfl(my0, bl + j + 6) * 32 + l];
        f16x4 v7 = f4[(long long)__shfl(my0, bl + j + 7) * 32 + l];
        a0 += (((float)v0[0] + (float)v1[0]) + ((float)v2[0] + (float)v3[0]))
            + (((float)v4[0] + (float)v5[0]) + ((float)v6[0] + (float)v7[0]));
        a1 += (((float)v0[1] + (float)v1[1]) + ((float)v2[1] + (float)v3[1]))
            + (((float)v4[1] + (float)v5[1]) + ((float)v6[1] + (float)v7[1]));
        a2 += (((float)v0[2] + (float)v1[2]) + ((float)v2[2] + (float)v3[2]))
            + (((float)v4[2] + (float)v5[2]) + ((float)v6[2] + (float)v7[2]));
        a3 += (((float)v0[3] + (float)v1[3]) + ((float)v2[3] + (float)v3[3]))
            + (((float)v4[3] + (float)v5[3]) + ((float)v6[3] + (float)v7[3]));
    }
    for (; j < lim0; j++) {
        f16x4 v = f4[(long long)__shfl(my0, bl + j) * 32 + l];
        a0 += (float)v[0]; a1 += (float)v[1]; a2 += (float)v[2]; a3 += (float)v[3];
    }
    for (; j + 8 <= n_it; j += 8) {
        f16x4 v0 = f4[(long long)__shfl(my1, bl + j - 32 + 0) * 32 + l];
        f16x4 v1 = f4[(long long)__shfl(my1, bl + j - 32 + 1) * 32 + l];
        f16x4 v2 = f4[(long long)__shfl(my1, bl + j - 32 + 2) * 32 + l];
        f16x4 v3 = f4[(long long)__shfl(my1, bl + j - 32 + 3) * 32 + l];
        f16x4 v4 = f4[(long long)__shfl(my1, bl + j - 32 + 4) * 32 + l];
        f16x4 v5 = f4[(long long)__shfl(my1, bl + j - 32 + 5) * 32 + l];
        f16x4 v6 = f4[(long long)__shfl(my1, bl + j - 32 + 6) * 32 + l];
        f16x4 v7 = f4[(long long)__shfl(my1, bl + j - 32 + 7) * 32 + l];
        a0 += (((float)v0[0] + (float)v1[0]) + ((float)v2[0] + (float)v3[0]))
            + (((float)v4[0] + (float)v5[0]) + ((float)v6[0] + (float)v7[0]));
        a1 += (((float)v0[1] + (float)v1[1]) + ((float)v2[1] + (float)v3[1]))
            + (((float)v4[1] + (float)v5[1]) + ((float)v6[1] + (float)v7[1]));
        a2 += (((float)v0[2] + (float)v1[2]) + ((float)v2[2] + (float)v3[2]))
            + (((float)v4[2] + (float)v5[2]) + ((float)v6[2] + (float)v7[2]));
        a3 += (((float)v0[3] + (float)v1[3]) + ((float)v2[3] + (float)v3[3]))
            + (((float)v4[3] + (float)v5[3]) + ((float)v6[3] + (float)v7[3]));
    }
    for (; j < n_it; j++) {
        f16x4 v = f4[(long long)__shfl(my1, bl + j - 32) * 32 + l];
        a0 += (float)v[0]; a1 += (float)v[1]; a2 += (float)v[2]; a3 += (float)v[3];
    }
    float inv = 1.f / fmaxf((float)deg, 1.f);
    f16x4 r;
    r[0] = (f16)(a0 * inv); r[1] = (f16)(a1 * inv);
    r[2] = (f16)(a2 * inv); r[3] = (f16)(a3 * inv);
    ((f16x4*)outb)[(long long)node * 32 + l] = r;
}

// ---------------------------------------------------------------------------
// SAGE layer-1 via f16 MFMA: h1 = relu(bn1(mean@W1l^T+b1+x@W1r^T))
// ---------------------------------------------------------------------------
__global__ __launch_bounds__(256) void sage1_kernel(
    const f16* __restrict__ Am, const f16* __restrict__ Ax,
    const f16* __restrict__ W1,
    const float* __restrict__ bias, const float* __restrict__ gamma,
    const float* __restrict__ beta, const float* __restrict__ bmean,
    const float* __restrict__ bvar, f16* __restrict__ C) {
    int tid  = threadIdx.x;
    int wave = tid >> 6;
    int lane = tid & 63;
    int m_base = blockIdx.x * 128 + wave * 32;
    int lrow = lane & 15;
    int lchunk = lane >> 4;

    f32x4 acc[2][8] = {};

#pragma unroll
    for (int phase = 0; phase < 2; phase++) {
        const f16* A = phase ? Ax : Am;
        const f16* Wp = W1 + phase * 128;
        f16x8 afrag[4][2];
#pragma unroll
        for (int kc = 0; kc < 4; kc++)
#pragma unroll
            for (int mf = 0; mf < 2; mf++) {
                int row = m_base + mf * 16 + lrow;
                row = row < N_NODES ? row : N_NODES - 1;
                afrag[kc][mf] = *(const f16x8*)(A + (long long)row * 128 + kc * 32 + lchunk * 8);
            }
#pragma unroll
        for (int nf = 0; nf < 8; nf++)
#pragma unroll
            for (int kc = 0; kc < 4; kc++) {
                f16x8 b = *(const f16x8*)(Wp + (long long)(nf * 16 + lrow) * 256
                                          + kc * 32 + lchunk * 8);
                acc[0][nf] = __builtin_amdgcn_mfma_f32_16x16x32_f16(afrag[kc][0], b, acc[0][nf], 0, 0, 0);
                acc[1][nf] = __builtin_amdgcn_mfma_f32_16x16x32_f16(afrag[kc][1], b, acc[1][nf], 0, 0, 0);
            }
    }

#pragma unroll
    for (int nf = 0; nf < 8; nf++) {
        int n = nf * 16 + lrow;
        float mul = gamma[n] * rsqrtf(bvar[n] + 1e-5f);
        float add = (bias[n] - bmean[n]) * mul + beta[n];
#pragma unroll
        for (int mf = 0; mf < 2; mf++)
#pragma unroll
            for (int r = 0; r < 4; r++) {
                int m = m_base + mf * 16 + lchunk * 4 + r;
                if (m < N_NODES) {
                    float v = fmaxf(fmaf(acc[mf][nf][r], mul, add), 0.f);
                    C[(long long)m * 128 + n] = (f16)v;
                }
            }
    }
}

// ---------------------------------------------------------------------------
// Pre-transform for layer 2: y2 = [h1@W2l^T | h1@W2r^T], K=128, streaming.
// ---------------------------------------------------------------------------
__global__ __launch_bounds__(256) void y2_kernel(const f16* __restrict__ h1,
                                                 const f16* __restrict__ W2cat,
                                                 f16* __restrict__ y2) {
    int tid  = threadIdx.x;
    int wave = tid >> 6;
    int lane = tid & 63;
    int m_base = blockIdx.x * 128 + wave * 32;
    int lrow = lane & 15;
    int lchunk = lane >> 4;

    f16x8 afrag[4][2];
#pragma unroll
    for (int kc = 0; kc < 4; kc++)
#pragma unroll
        for (int mf = 0; mf < 2; mf++) {
            int row = m_base + mf * 16 + lrow;
            row = row < N_NODES ? row : N_NODES - 1;
            afrag[kc][mf] = *(const f16x8*)(h1 + (long long)row * 128 + kc * 32 + lchunk * 8);
        }

#pragma unroll
    for (int nf = 0; nf < 8; nf++) {
        f32x4 acc[2] = {};
#pragma unroll
        for (int kc = 0; kc < 4; kc++) {
            f16x8 b = *(const f16x8*)(W2cat + (long long)(nf * 16 + lrow) * 128
                                      + kc * 32 + lchunk * 8);
            acc[0] = __builtin_amdgcn_mfma_f32_16x16x32_f16(afrag[kc][0], b, acc[0], 0, 0, 0);
            acc[1] = __builtin_amdgcn_mfma_f32_16x16x32_f16(afrag[kc][1], b, acc[1], 0, 0, 0);
        }
        int n = nf * 16 + lrow;
#pragma unroll
        for (int mf = 0; mf < 2; mf++)
#pragma unroll
            for (int r = 0; r < 4; r++) {
                int m = m_base + mf * 16 + lchunk * 4 + r;
                if (m < N_NODES) y2[(long long)m * 128 + n] = (f16)acc[mf][r];
            }
    }
}

// ---------------------------------------------------------------------------
// Fused layer-2 tail: per block of 128 nodes,
//   phase 1: 16-lane groups aggregate y2l half-rows (mean), add y2r, BN2+ReLU
//            -> LDS tile (mean2 never touches global)
//   phase 2: 64->10 head, write logits.
// ---------------------------------------------------------------------------
__global__ __launch_bounds__(256) void agg_final_kernel(
    const f16* __restrict__ y2,
    const int* __restrict__ cnt,
    const unsigned short* __restrict__ bucket,
    const float* __restrict__ b2,
    const float* __restrict__ gamma,
    const float* __restrict__ beta,
    const float* __restrict__ bmean,
    const float* __restrict__ bvar,
    const float* __restrict__ hw,
    const float* __restrict__ hb,
    float* __restrict__ outp) {
    __shared__ f16 sm[128][68];
    int t = threadIdx.x;
    int l  = t & 15;          // lane within 16-lane group
    int bl = t & 48;          // group base lane within wave
    int grp = t >> 4;         // 0..15

    // per-lane BN constants for channels l*4..l*4+3 (same for every node)
    float mul4[4], add4[4];
#pragma unroll
    for (int i = 0; i < 4; i++) {
        int n = l * 4 + i;
        mul4[i] = gamma[n] * rsqrtf(bvar[n] + 1e-5f);
        add4[i] = (b2[n] - bmean[n]) * mul4[i] + beta[n];
    }

    const f16x4* f4 = (const f16x4*)y2;   // row = 32 quads; quads 0..15 = y2l

    for (int it = 0; it < 8; it++) {
        int nloc = it * 16 + grp;
        int node = blockIdx.x * 128 + nloc;
        if (node < N_NODES) {
            int deg = cnt[node];
            int n_it = deg < CAP ? deg : CAP;
            const unsigned short* b = bucket + (long long)node * CAP;
            int my0 = (l < n_it)      ? (int)b[l]      : 0;
            int my1 = (16 + l < n_it) ? (int)b[16 + l] : 0;
            int my2 = (32 + l < n_it) ? (int)b[32 + l] : 0;
            int my3 = (48 + l < n_it) ? (int)b[48 + l] : 0;
            float a0 = 0.f, a1 = 0.f, a2 = 0.f, a3 = 0.f;
            int j = 0;
#define AGG_SEC(MYREG, BASE)                                                     \
            {                                                                    \
                int lim = n_it < (BASE + 16) ? n_it : (BASE + 16);               \
                for (; j + 4 <= lim; j += 4) {                                   \
                    f16x4 v0 = f4[(long long)__shfl(MYREG, bl + j - BASE + 0) * 32 + l]; \
                    f16x4 v1 = f4[(long long)__shfl(MYREG, bl + j - BASE + 1) * 32 + l]; \
                    f16x4 v2 = f4[(long long)__shfl(MYREG, bl + j - BASE + 2) * 32 + l]; \
                    f16x4 v3 = f4[(long long)__shfl(MYREG, bl + j - BASE + 3) * 32 + l]; \
                    a0 += ((float)v0[0] + (float)v1[0]) + ((float)v2[0] + (float)v3[0]); \
                    a1 += ((float)v0[1] + (float)v1[1]) + ((float)v2[1] + (float)v3[1]); \
                    a2 += ((float)v0[2] + (float)v1[2]) + ((float)v2[2] + (float)v3[2]); \
                    a3 += ((float)v0[3] + (float)v1[3]) + ((float)v2[3] + (float)v3[3]); \
                }                                                                \
                for (; j < lim; j++) {                                           \
                    f16x4 v = f4[(long long)__shfl(MYREG, bl + j - BASE) * 32 + l]; \
                    a0 += (float)v[0]; a1 += (float)v[1];                        \
                    a2 += (float)v[2]; a3 += (float)v[3];                        \
                }                                                                \
            }
            AGG_SEC(my0, 0)
            AGG_SEC(my1, 16)
            AGG_SEC(my2, 32)
            AGG_SEC(my3, 48)
#undef AGG_SEC
            float inv = 1.f / fmaxf((float)deg, 1.f);
            f16x4 yr = f4[(long long)node * 32 + 16 + l];   // y2r quad
            f16x4 r;
            r[0] = (f16)fmaxf(fmaf(a0 * inv + (float)yr[0], mul4[0], add4[0]), 0.f);
            r[1] = (f16)fmaxf(fmaf(a1 * inv + (float)yr[1], mul4[1], add4[1]), 0.f);
            r[2] = (f16)fmaxf(fmaf(a2 * inv + (float)yr[2], mul4[2], add4[2]), 0.f);
            r[3] = (f16)fmaxf(fmaf(a3 * inv + (float)yr[3], mul4[3], add4[3]), 0.f);
            *(f16x4*)&sm[nloc][l * 4] = r;
        }
    }
    __syncthreads();

    int rl = t >> 1, hh = t & 1;
    int m = blockIdx.x * 128 + rl;
    if (m < N_NODES) {
        int cb = hh * 5;
        float a0 = hb[cb + 0], a1 = hb[cb + 1], a2 = hb[cb + 2];
        float a3 = hb[cb + 3], a4 = hb[cb + 4];
#pragma unroll 8
        for (int k = 0; k < 64; k++) {
            float hv = (float)sm[rl][k];
            a0 = fmaf(hv, hw[(cb + 0) * 64 + k], a0);
            a1 = fmaf(hv, hw[(cb + 1) * 64 + k], a1);
            a2 = fmaf(hv, hw[(cb + 2) * 64 + k], a2);
            a3 = fmaf(hv, hw[(cb + 3) * 64 + k], a3);
            a4 = fmaf(hv, hw[(cb + 4) * 64 + k], a4);
        }
        float* op = outp + (long long)m * N_CLASSES + cb;
        op[0] = a0; op[1] = a1; op[2] = a2; op[3] = a3; op[4] = a4;
    }
}

// ---------------------------------------------------------------------------
extern "C" void kernel_launch(void* const* d_in, const int* in_sizes, int n_in,
                              void* d_out, int out_size, void* d_ws, size_t ws_size,
                              hipStream_t stream) {
    const float* x      = (const float*)d_in[0];
    const int*   ei     = (const int*)d_in[1];
    const float* w1l    = (const float*)d_in[2];
    const float* b1l    = (const float*)d_in[3];
    const float* w1r    = (const float*)d_in[4];
    const float* bn1_g  = (const float*)d_in[5];
    const float* bn1_b  = (const float*)d_in[6];
    const float* bn1_m  = (const float*)d_in[7];
    const float* bn1_v  = (const float*)d_in[8];
    const float* w2l    = (const float*)d_in[9];
    const float* b2l    = (const float*)d_in[10];
    const float* w2r    = (const float*)d_in[11];
    const float* bn2_g  = (const float*)d_in[12];
    const float* bn2_b  = (const float*)d_in[13];
    const float* bn2_m  = (const float*)d_in[14];
    const float* bn2_v  = (const float*)d_in[15];
    const float* head_w = (const float*)d_in[16];
    const float* head_b = (const float*)d_in[17];
    float* out = (float*)d_out;

    const int* src  = ei;
    const int* dstv = ei + N_EDGES;

    // workspace layout
    char* ws = (char*)d_ws;
    size_t off = 0;
    int* cnt               = (int*)(ws + off); off += ((size_t)N_NODES * 4 + 511) & ~511ull;
    unsigned short* bucket = (unsigned short*)(ws + off); off += (size_t)N_NODES * CAP * 2;
    f16* xh     = (f16*)(ws + off); off += (size_t)N_NODES * 128 * 2;
    f16* meanb  = (f16*)(ws + off); off += (size_t)N_NODES * 128 * 2;
    f16* h1     = (f16*)(ws + off); off += (size_t)N_NODES * 128 * 2;
    f16* y2     = (f16*)(ws + off); off += (size_t)N_NODES * 128 * 2;
    f16* W1     = (f16*)(ws + off); off += (size_t)128 * 256 * 2;
    f16* W2cat  = (f16*)(ws + off); off += (size_t)128 * 128 * 2;

    // --- fused bucket build + f16 conversion ---
    zero_cnt_kernel<<<(N_NODES / 4 + 255) / 256, 256, 0, stream>>>(cnt);
    build_fused_kernel<<<EB4 + XB + 4, 256, 0, stream>>>(
        src, dstv, cnt, bucket, x, w1l, w1r, w2l, w2r, xh, W1, W2cat);

    // --- layer 1 ---
    agg_mean_f16_kernel<<<N_NODES / 8, 256, 0, stream>>>(xh, cnt, bucket, meanb);
    sage1_kernel<<<(N_NODES + 127) / 128, 256, 0, stream>>>(
        meanb, xh, W1, b1l, bn1_g, bn1_b, bn1_m, bn1_v, h1);

    // --- layer-2 pre-transform + fused aggregate/head ---
    y2_kernel<<<(N_NODES + 127) / 128, 256, 0, stream>>>(h1, W2cat, y2);
    agg_final_kernel<<<(N_NODES + 127) / 128, 256, 0, stream>>>(
        y2, cnt, bucket, b2l, bn2_g, bn2_b, bn2_m, bn2_v, head_w, head_b, out);
}

// Round 14
// 149.992 us; speedup vs baseline: 1.1787x; 1.1787x over previous
//
#include <hip/hip_runtime.h>

typedef _Float16 f16;
typedef _Float16 f16x4 __attribute__((ext_vector_type(4)));
typedef _Float16 f16x8 __attribute__((ext_vector_type(8)));
typedef float f32x4 __attribute__((ext_vector_type(4)));

#define N_NODES 50000
#define N_EDGES 800000
#define N_CLASSES 10
#define CAP 64           // per-node bucket capacity; deg~Poisson(16), P(>=64)~e^-128
#define EDGE_BLOCKS ((N_EDGES + 255) / 256)        // 3125

// ---------------------------------------------------------------------------
// Zero the degree counters (~2us; rocclr fillBuffer was ~40us)
// ---------------------------------------------------------------------------
__global__ void zero_cnt_kernel(int* __restrict__ cnt) {
    int i = blockIdx.x * 256 + threadIdx.x;
    if (i < N_NODES / 4) ((int4*)cnt)[i] = make_int4(0, 0, 0, 0);
}

// ---------------------------------------------------------------------------
// Fused build (R11-proven): even blocks fill buckets (atomic-latency), odd
// blocks convert x to f16 (bandwidth) — interleave keeps both co-resident.
// ---------------------------------------------------------------------------
__global__ void build_fused_kernel(const int* __restrict__ src, const int* __restrict__ dst,
                                   int* __restrict__ cnt, unsigned short* __restrict__ bucket,
                                   const float* __restrict__ x,
                                   const float* __restrict__ w1l, const float* __restrict__ w1r,
                                   const float* __restrict__ w2l, const float* __restrict__ w2r,
                                   f16* __restrict__ xh, f16* __restrict__ W1, f16* __restrict__ W2cat) {
    int bid = blockIdx.x;
    if (bid < 2 * EDGE_BLOCKS) {
        int half = bid >> 1;
        if ((bid & 1) == 0) {
            int e = half * 256 + threadIdx.x;
            if (e < N_EDGES) {
                int d = dst[e];
                int s = atomicAdd(&cnt[d], 1);
                if (s < CAP) bucket[(long long)d * CAP + s] = (unsigned short)src[e];
            }
        } else {
            long long base = ((long long)half * 256 + threadIdx.x) * 8;
            float4 a = *(const float4*)(x + base);
            float4 b = *(const float4*)(x + base + 4);
            f16x8 o;
            o[0] = (f16)a.x; o[1] = (f16)a.y; o[2] = (f16)a.z; o[3] = (f16)a.w;
            o[4] = (f16)b.x; o[5] = (f16)b.y; o[6] = (f16)b.z; o[7] = (f16)b.w;
            *(f16x8*)(xh + base) = o;
        }
    } else {
        int wt = (bid - 2 * EDGE_BLOCKS) * 256 + threadIdx.x;   // 0..1023
        for (int idx = wt; idx < 128 * 256; idx += 1024) {
            int n = idx >> 8, k = idx & 255;
            W1[idx] = (f16)(k < 128 ? w1l[n * 128 + k] : w1r[n * 128 + k - 128]);
        }
        for (int idx = wt; idx < 128 * 128; idx += 1024) {
            int n = idx >> 7, k = idx & 127;
            W2cat[idx] = (f16)(n < 64 ? w2l[n * 128 + k] : w2r[(n - 64) * 128 + k]);
        }
    }
}

// ---------------------------------------------------------------------------
// Layer-1 aggregation (R11-proven): 2 nodes/wave, 32 lanes x f16x4 (8B).
// ---------------------------------------------------------------------------
__global__ void agg_mean_f16_kernel(const f16* __restrict__ feat,
                                    const int* __restrict__ cnt,
                                    const unsigned short* __restrict__ bucket,
                                    f16* __restrict__ outb) {
    int node = blockIdx.x * 8 + (threadIdx.x >> 5);
    int l  = threadIdx.x & 31;
    int bl = threadIdx.x & 32;
    int deg = cnt[node];
    int n_it = deg < CAP ? deg : CAP;
    const unsigned short* b = bucket + (long long)node * CAP;
    int my0 = (l < n_it)      ? (int)b[l]      : 0;
    int my1 = (32 + l < n_it) ? (int)b[32 + l] : 0;
    const f16x4* f4 = (const f16x4*)feat;
    float a0 = 0.f, a1 = 0.f, a2 = 0.f, a3 = 0.f;
    int j = 0;
    int lim0 = n_it < 32 ? n_it : 32;
    for (; j + 8 <= lim0; j += 8) {
        f16x4 v0 = f4[(long long)__shfl(my0, bl + j + 0) * 32 + l];
        f16x4 v1 = f4[(long long)__shfl(my0, bl + j + 1) * 32 + l];
        f16x4 v2 = f4[(long long)__shfl(my0, bl + j + 2) * 32 + l];
        f16x4 v3 = f4[(long long)__shfl(my0, bl + j + 3) * 32 + l];
        f16x4 v4 = f4[(long long)__shfl(my0, bl + j + 4) * 32 + l];
        f16x4 v5 = f4[(long long)__shfl(my0, bl + j + 5) * 32 + l];
        f16x4 v6 = f4[(long long)__shfl(my0, bl + j + 6) * 32 + l];
        f16x4 v7 = f4[(long long)__shfl(my0, bl + j + 7) * 32 + l];
        a0 += (((float)v0[0] + (float)v1[0]) + ((float)v2[0] + (float)v3[0]))
            + (((float)v4[0] + (float)v5[0]) + ((float)v6[0] + (float)v7[0]));
        a1 += (((float)v0[1] + (float)v1[1]) + ((float)v2[1] + (float)v3[1]))
            + (((float)v4[1] + (float)v5[1]) + ((float)v6[1] + (float)v7[1]));
        a2 += (((float)v0[2] + (float)v1[2]) + ((float)v2[2] + (float)v3[2]))
            + (((float)v4[2] + (float)v5[2]) + ((float)v6[2] + (float)v7[2]));
        a3 += (((float)v0[3] + (float)v1[3]) + ((float)v2[3] + (float)v3[3]))
            + (((float)v4[3] + (float)v5[3]) + ((float)v6[3] + (float)v7[3]));
    }
    for (; j < lim0; j++) {
        f16x4 v = f4[(long long)__shfl(my0, bl + j) * 32 + l];
        a0 += (float)v[0]; a1 += (float)v[1]; a2 += (float)v[2]; a3 += (float)v[3];
    }
    for (; j + 8 <= n_it; j += 8) {
        f16x4 v0 = f4[(long long)__shfl(my1, bl + j - 32 + 0) * 32 + l];
        f16x4 v1 = f4[(long long)__shfl(my1, bl + j - 32 + 1) * 32 + l];
        f16x4 v2 = f4[(long long)__shfl(my1, bl + j - 32 + 2) * 32 + l];
        f16x4 v3 = f4[(long long)__shfl(my1, bl + j - 32 + 3) * 32 + l];
        f16x4 v4 = f4[(long long)__shfl(my1, bl + j - 32 + 4) * 32 + l];
        f16x4 v5 = f4[(long long)__shfl(my1, bl + j - 32 + 5) * 32 + l];
        f16x4 v6 = f4[(long long)__shfl(my1, bl + j - 32 + 6) * 32 + l];
        f16x4 v7 = f4[(long long)__shfl(my1, bl + j - 32 + 7) * 32 + l];
        a0 += (((float)v0[0] + (float)v1[0]) + ((float)v2[0] + (float)v3[0]))
            + (((float)v4[0] + (float)v5[0]) + ((float)v6[0] + (float)v7[0]));
        a1 += (((float)v0[1] + (float)v1[1]) + ((float)v2[1] + (float)v3[1]))
            + (((float)v4[1] + (float)v5[1]) + ((float)v6[1] + (float)v7[1]));
        a2 += (((float)v0[2] + (float)v1[2]) + ((float)v2[2] + (float)v3[2]))
            + (((float)v4[2] + (float)v5[2]) + ((float)v6[2] + (float)v7[2]));
        a3 += (((float)v0[3] + (float)v1[3]) + ((float)v2[3] + (float)v3[3]))
            + (((float)v4[3] + (float)v5[3]) + ((float)v6[3] + (float)v7[3]));
    }
    for (; j < n_it; j++) {
        f16x4 v = f4[(long long)__shfl(my1, bl + j - 32) * 32 + l];
        a0 += (float)v[0]; a1 += (float)v[1]; a2 += (float)v[2]; a3 += (float)v[3];
    }
    float inv = 1.f / fmaxf((float)deg, 1.f);
    f16x4 r;
    r[0] = (f16)(a0 * inv); r[1] = (f16)(a1 * inv);
    r[2] = (f16)(a2 * inv); r[3] = (f16)(a3 * inv);
    ((f16x4*)outb)[(long long)node * 32 + l] = r;
}

// ---------------------------------------------------------------------------
// Fused layer-1 + layer-2 pre-transform (per-block dependency is exact):
// Stage 1: h1 = relu(bn1(mean@W1l^T+b1+x@W1r^T)) -> per-wave LDS tile
// Stage 2: y2 = [h1@W2l^T | h1@W2r^T] -> global (h1 never hits HBM).
// Same-wave LDS write->read; no barrier. Grid stays 391 blocks (MFMA-bound).
// ---------------------------------------------------------------------------
__global__ __launch_bounds__(256) void sage1_y2_kernel(
    const f16* __restrict__ Am, const f16* __restrict__ Ax,
    const f16* __restrict__ W1,
    const float* __restrict__ bias, const float* __restrict__ gamma,
    const float* __restrict__ beta, const float* __restrict__ bmean,
    const float* __restrict__ bvar,
    const f16* __restrict__ W2cat,  // [128][128]
    f16* __restrict__ y2) {
    __shared__ f16 ldsA[4][32][136];

    int tid  = threadIdx.x;
    int wave = tid >> 6;
    int lane = tid & 63;
    int m_base = blockIdx.x * 128 + wave * 32;
    int lrow = lane & 15;
    int lchunk = lane >> 4;

    f32x4 acc[2][8] = {};

#pragma unroll
    for (int phase = 0; phase < 2; phase++) {
        const f16* A = phase ? Ax : Am;
        const f16* Wp = W1 + phase * 128;
        f16x8 afrag[4][2];
#pragma unroll
        for (int kc = 0; kc < 4; kc++)
#pragma unroll
            for (int mf = 0; mf < 2; mf++) {
                int row = m_base + mf * 16 + lrow;
                row = row < N_NODES ? row : N_NODES - 1;
                afrag[kc][mf] = *(const f16x8*)(A + (long long)row * 128 + kc * 32 + lchunk * 8);
            }
#pragma unroll
        for (int nf = 0; nf < 8; nf++)
#pragma unroll
            for (int kc = 0; kc < 4; kc++) {
                f16x8 b = *(const f16x8*)(Wp + (long long)(nf * 16 + lrow) * 256
                                          + kc * 32 + lchunk * 8);
                acc[0][nf] = __builtin_amdgcn_mfma_f32_16x16x32_f16(afrag[kc][0], b, acc[0][nf], 0, 0, 0);
                acc[1][nf] = __builtin_amdgcn_mfma_f32_16x16x32_f16(afrag[kc][1], b, acc[1][nf], 0, 0, 0);
            }
    }

    // BN1 + ReLU -> per-wave LDS tile
#pragma unroll
    for (int nf = 0; nf < 8; nf++) {
        int n = nf * 16 + lrow;
        float mul = gamma[n] * rsqrtf(bvar[n] + 1e-5f);
        float add = (bias[n] - bmean[n]) * mul + beta[n];
#pragma unroll
        for (int mf = 0; mf < 2; mf++)
#pragma unroll
            for (int r = 0; r < 4; r++) {
                int rloc = mf * 16 + lchunk * 4 + r;
                ldsA[wave][rloc][n] = (f16)fmaxf(fmaf(acc[mf][nf][r], mul, add), 0.f);
            }
    }

    // Stage 2: y2 = h1_tile @ W2cat^T (K=128)
#pragma unroll
    for (int nf2 = 0; nf2 < 8; nf2++) {
        f32x4 acc2[2] = {};
#pragma unroll
        for (int kc = 0; kc < 4; kc++) {
            f16x8 b2 = *(const f16x8*)(W2cat + (long long)(nf2 * 16 + lrow) * 128
                                       + kc * 32 + lchunk * 8);
            f16x8 a0 = *(const f16x8*)&ldsA[wave][lrow][kc * 32 + lchunk * 8];
            f16x8 a1 = *(const f16x8*)&ldsA[wave][16 + lrow][kc * 32 + lchunk * 8];
            acc2[0] = __builtin_amdgcn_mfma_f32_16x16x32_f16(a0, b2, acc2[0], 0, 0, 0);
            acc2[1] = __builtin_amdgcn_mfma_f32_16x16x32_f16(a1, b2, acc2[1], 0, 0, 0);
        }
        int n = nf2 * 16 + lrow;
#pragma unroll
        for (int mf = 0; mf < 2; mf++)
#pragma unroll
            for (int r = 0; r < 4; r++) {
                int m = m_base + mf * 16 + lchunk * 4 + r;
                if (m < N_NODES) y2[(long long)m * 128 + n] = (f16)acc2[mf][r];
            }
    }
}

// ---------------------------------------------------------------------------
// Layer-2 aggregation over y2l half-rows (R11-proven): 4 nodes/wave,
// 16 lanes x f16x4.
// ---------------------------------------------------------------------------
__global__ void agg_half_kernel(const f16* __restrict__ y2,
                                const int* __restrict__ cnt,
                                const unsigned short* __restrict__ bucket,
                                f16* __restrict__ mean2) {
    int node = blockIdx.x * 16 + (threadIdx.x >> 4);
    int l  = threadIdx.x & 15;
    int bl = threadIdx.x & 48;
    int deg = cnt[node];
    int n_it = deg < CAP ? deg : CAP;
    const unsigned short* b = bucket + (long long)node * CAP;
    int my0 = (l < n_it)      ? (int)b[l]      : 0;
    int my1 = (16 + l < n_it) ? (int)b[16 + l] : 0;
    int my2 = (32 + l < n_it) ? (int)b[32 + l] : 0;
    int my3 = (48 + l < n_it) ? (int)b[48 + l] : 0;
    const f16x4* f4 = (const f16x4*)y2;
    float a0 = 0.f, a1 = 0.f, a2 = 0.f, a3 = 0.f;
    int j = 0;

#define AGG_SEC(MYREG, BASE)                                                     \
    {                                                                            \
        int lim = n_it < (BASE + 16) ? n_it : (BASE + 16);                       \
        for (; j + 8 <= lim; j += 8) {                                           \
            f16x4 v0 = f4[(long long)__shfl(MYREG, bl + j - BASE + 0) * 32 + l]; \
            f16x4 v1 = f4[(long long)__shfl(MYREG, bl + j - BASE + 1) * 32 + l]; \
            f16x4 v2 = f4[(long long)__shfl(MYREG, bl + j - BASE + 2) * 32 + l]; \
            f16x4 v3 = f4[(long long)__shfl(MYREG, bl + j - BASE + 3) * 32 + l]; \
            f16x4 v4 = f4[(long long)__shfl(MYREG, bl + j - BASE + 4) * 32 + l]; \
            f16x4 v5 = f4[(long long)__shfl(MYREG, bl + j - BASE + 5) * 32 + l]; \
            f16x4 v6 = f4[(long long)__shfl(MYREG, bl + j - BASE + 6) * 32 + l]; \
            f16x4 v7 = f4[(long long)__shfl(MYREG, bl + j - BASE + 7) * 32 + l]; \
            a0 += (((float)v0[0] + (float)v1[0]) + ((float)v2[0] + (float)v3[0]))\
                + (((float)v4[0] + (float)v5[0]) + ((float)v6[0] + (float)v7[0]));\
            a1 += (((float)v0[1] + (float)v1[1]) + ((float)v2[1] + (float)v3[1]))\
                + (((float)v4[1] + (float)v5[1]) + ((float)v6[1] + (float)v7[1]));\
            a2 += (((float)v0[2] + (float)v1[2]) + ((float)v2[2] + (float)v3[2]))\
                + (((float)v4[2] + (float)v5[2]) + ((float)v6[2] + (float)v7[2]));\
            a3 += (((float)v0[3] + (float)v1[3]) + ((float)v2[3] + (float)v3[3]))\
                + (((float)v4[3] + (float)v5[3]) + ((float)v6[3] + (float)v7[3]));\
        }                                                                        \
        for (; j < lim; j++) {                                                   \
            f16x4 v = f4[(long long)__shfl(MYREG, bl + j - BASE) * 32 + l];      \
            a0 += (float)v[0]; a1 += (float)v[1];                                \
            a2 += (float)v[2]; a3 += (float)v[3];                                \
        }                                                                        \
    }

    AGG_SEC(my0, 0)
    AGG_SEC(my1, 16)
    AGG_SEC(my2, 32)
    AGG_SEC(my3, 48)
#undef AGG_SEC

    float inv = 1.f / fmaxf((float)deg, 1.f);
    f16x4 r;
    r[0] = (f16)(a0 * inv); r[1] = (f16)(a1 * inv);
    r[2] = (f16)(a2 * inv); r[3] = (f16)(a3 * inv);
    ((f16x4*)mean2)[(long long)node * 16 + l] = r;
}

// ---------------------------------------------------------------------------
// Final: out = head( relu(bn2( mean2 + b2l + y2r )) )  (R11-proven)
// ---------------------------------------------------------------------------
__global__ void final_head_kernel(const f16* __restrict__ mean2,
                                  const f16* __restrict__ y2,
                                  const float* __restrict__ b2,
                                  const float* __restrict__ gamma,
                                  const float* __restrict__ beta,
                                  const float* __restrict__ bmean,
                                  const float* __restrict__ bvar,
                                  const float* __restrict__ hw,
                                  const float* __restrict__ hb,
                                  float* __restrict__ outp) {
    __shared__ f16 sm[128][68];
    int t = threadIdx.x;
    int rl = t >> 1, hh = t & 1;
    int m = blockIdx.x * 128 + rl;
    if (m < N_NODES) {
        int ch0 = hh * 32;
#pragma unroll
        for (int c = 0; c < 32; c += 8) {
            int ch = ch0 + c;
            f16x8 mv = *(const f16x8*)(mean2 + (long long)m * 64 + ch);
            f16x8 yv = *(const f16x8*)(y2 + (long long)m * 128 + 64 + ch);
#pragma unroll
            for (int i = 0; i < 8; i++) {
                int n = ch + i;
                float mul = gamma[n] * rsqrtf(bvar[n] + 1e-5f);
                float add = (b2[n] - bmean[n]) * mul + beta[n];
                float v = fmaf((float)mv[i] + (float)yv[i], mul, add);
                sm[rl][n] = (f16)fmaxf(v, 0.f);
            }
        }
    }
    __syncthreads();
    if (m < N_NODES) {
        int cb = hh * 5;
        float a0 = hb[cb + 0], a1 = hb[cb + 1], a2 = hb[cb + 2];
        float a3 = hb[cb + 3], a4 = hb[cb + 4];
#pragma unroll 8
        for (int k = 0; k < 64; k++) {
            float hv = (float)sm[rl][k];
            a0 = fmaf(hv, hw[(cb + 0) * 64 + k], a0);
            a1 = fmaf(hv, hw[(cb + 1) * 64 + k], a1);
            a2 = fmaf(hv, hw[(cb + 2) * 64 + k], a2);
            a3 = fmaf(hv, hw[(cb + 3) * 64 + k], a3);
            a4 = fmaf(hv, hw[(cb + 4) * 64 + k], a4);
        }
        float* op = outp + (long long)m * N_CLASSES + cb;
        op[0] = a0; op[1] = a1; op[2] = a2; op[3] = a3; op[4] = a4;
    }
}

// ---------------------------------------------------------------------------
extern "C" void kernel_launch(void* const* d_in, const int* in_sizes, int n_in,
                              void* d_out, int out_size, void* d_ws, size_t ws_size,
                              hipStream_t stream) {
    const float* x      = (const float*)d_in[0];
    const int*   ei     = (const int*)d_in[1];
    const float* w1l    = (const float*)d_in[2];
    const float* b1l    = (const float*)d_in[3];
    const float* w1r    = (const float*)d_in[4];
    const float* bn1_g  = (const float*)d_in[5];
    const float* bn1_b  = (const float*)d_in[6];
    const float* bn1_m  = (const float*)d_in[7];
    const float* bn1_v  = (const float*)d_in[8];
    const float* w2l    = (const float*)d_in[9];
    const float* b2l    = (const float*)d_in[10];
    const float* w2r    = (const float*)d_in[11];
    const float* bn2_g  = (const float*)d_in[12];
    const float* bn2_b  = (const float*)d_in[13];
    const float* bn2_m  = (const float*)d_in[14];
    const float* bn2_v  = (const float*)d_in[15];
    const float* head_w = (const float*)d_in[16];
    const float* head_b = (const float*)d_in[17];
    float* out = (float*)d_out;

    const int* src  = ei;
    const int* dstv = ei + N_EDGES;

    // workspace layout
    char* ws = (char*)d_ws;
    size_t off = 0;
    int* cnt               = (int*)(ws + off); off += ((size_t)N_NODES * 4 + 511) & ~511ull;
    unsigned short* bucket = (unsigned short*)(ws + off); off += (size_t)N_NODES * CAP * 2;
    f16* xh     = (f16*)(ws + off); off += (size_t)N_NODES * 128 * 2;
    f16* meanb  = (f16*)(ws + off); off += (size_t)N_NODES * 128 * 2;
    f16* y2     = (f16*)(ws + off); off += (size_t)N_NODES * 128 * 2;
    f16* mean2  = (f16*)(ws + off); off += (size_t)N_NODES * 64 * 2;
    f16* W1     = (f16*)(ws + off); off += (size_t)128 * 256 * 2;
    f16* W2cat  = (f16*)(ws + off); off += (size_t)128 * 128 * 2;

    // --- fused bucket build + f16 conversion ---
    zero_cnt_kernel<<<(N_NODES / 4 + 255) / 256, 256, 0, stream>>>(cnt);
    build_fused_kernel<<<2 * EDGE_BLOCKS + 4, 256, 0, stream>>>(
        src, dstv, cnt, bucket, x, w1l, w1r, w2l, w2r, xh, W1, W2cat);

    // --- layer 1 + layer-2 pre-transform (fused) ---
    agg_mean_f16_kernel<<<N_NODES / 8, 256, 0, stream>>>(xh, cnt, bucket, meanb);
    sage1_y2_kernel<<<(N_NODES + 127) / 128, 256, 0, stream>>>(
        meanb, xh, W1, b1l, bn1_g, bn1_b, bn1_m, bn1_v, W2cat, y2);

    // --- layer-2 half-width aggregate + final head ---
    agg_half_kernel<<<N_NODES / 16, 256, 0, stream>>>(y2, cnt, bucket, mean2);
    final_head_kernel<<<(N_NODES + 127) / 128, 256, 0, stream>>>(
        mean2, y2, b2l, bn2_g, bn2_b, bn2_m, bn2_v, head_w, head_b, out);
}

// Round 15
// 140.117 us; speedup vs baseline: 1.2618x; 1.0705x over previous
//
#include <hip/hip_runtime.h>

typedef _Float16 f16;
typedef _Float16 f16x4 __attribute__((ext_vector_type(4)));
typedef _Float16 f16x8 __attribute__((ext_vector_type(8)));
typedef float f32x4 __attribute__((ext_vector_type(4)));

#define N_NODES 50000
#define N_EDGES 800000
#define N_CLASSES 10
#define CAP 64           // per-node bucket capacity; deg~Poisson(16), P(>=64)~e^-128
#define EDGE_BLOCKS ((N_EDGES + 255) / 256)        // 3125

// ---------------------------------------------------------------------------
// Zero the degree counters (~2us; rocclr fillBuffer was ~40us)
// ---------------------------------------------------------------------------
__global__ void zero_cnt_kernel(int* __restrict__ cnt) {
    int i = blockIdx.x * 256 + threadIdx.x;
    if (i < N_NODES / 4) ((int4*)cnt)[i] = make_int4(0, 0, 0, 0);
}

// ---------------------------------------------------------------------------
// Fused build (R11-proven): even blocks fill buckets (atomic-latency), odd
// blocks convert x to f16 (bandwidth) — interleave keeps both co-resident.
// ---------------------------------------------------------------------------
__global__ void build_fused_kernel(const int* __restrict__ src, const int* __restrict__ dst,
                                   int* __restrict__ cnt, unsigned short* __restrict__ bucket,
                                   const float* __restrict__ x,
                                   const float* __restrict__ w1l, const float* __restrict__ w1r,
                                   const float* __restrict__ w2l, const float* __restrict__ w2r,
                                   f16* __restrict__ xh, f16* __restrict__ W1, f16* __restrict__ W2cat) {
    int bid = blockIdx.x;
    if (bid < 2 * EDGE_BLOCKS) {
        int half = bid >> 1;
        if ((bid & 1) == 0) {
            int e = half * 256 + threadIdx.x;
            if (e < N_EDGES) {
                int d = dst[e];
                int s = atomicAdd(&cnt[d], 1);
                if (s < CAP) bucket[(long long)d * CAP + s] = (unsigned short)src[e];
            }
        } else {
            long long base = ((long long)half * 256 + threadIdx.x) * 8;
            float4 a = *(const float4*)(x + base);
            float4 b = *(const float4*)(x + base + 4);
            f16x8 o;
            o[0] = (f16)a.x; o[1] = (f16)a.y; o[2] = (f16)a.z; o[3] = (f16)a.w;
            o[4] = (f16)b.x; o[5] = (f16)b.y; o[6] = (f16)b.z; o[7] = (f16)b.w;
            *(f16x8*)(xh + base) = o;
        }
    } else {
        int wt = (bid - 2 * EDGE_BLOCKS) * 256 + threadIdx.x;   // 0..1023
        for (int idx = wt; idx < 128 * 256; idx += 1024) {
            int n = idx >> 8, k = idx & 255;
            W1[idx] = (f16)(k < 128 ? w1l[n * 128 + k] : w1r[n * 128 + k - 128]);
        }
        for (int idx = wt; idx < 128 * 128; idx += 1024) {
            int n = idx >> 7, k = idx & 127;
            W2cat[idx] = (f16)(n < 64 ? w2l[n * 128 + k] : w2r[(n - 64) * 128 + k]);
        }
    }
}

// ---------------------------------------------------------------------------
// Layer-1 aggregation (R11-proven): 2 nodes/wave, 32 lanes x f16x4 (8B).
// ---------------------------------------------------------------------------
__global__ void agg_mean_f16_kernel(const f16* __restrict__ feat,
                                    const int* __restrict__ cnt,
                                    const unsigned short* __restrict__ bucket,
                                    f16* __restrict__ outb) {
    int node = blockIdx.x * 8 + (threadIdx.x >> 5);
    int l  = threadIdx.x & 31;
    int bl = threadIdx.x & 32;
    int deg = cnt[node];
    int n_it = deg < CAP ? deg : CAP;
    const unsigned short* b = bucket + (long long)node * CAP;
    int my0 = (l < n_it)      ? (int)b[l]      : 0;
    int my1 = (32 + l < n_it) ? (int)b[32 + l] : 0;
    const f16x4* f4 = (const f16x4*)feat;
    float a0 = 0.f, a1 = 0.f, a2 = 0.f, a3 = 0.f;
    int j = 0;
    int lim0 = n_it < 32 ? n_it : 32;
    for (; j + 8 <= lim0; j += 8) {
        f16x4 v0 = f4[(long long)__shfl(my0, bl + j + 0) * 32 + l];
        f16x4 v1 = f4[(long long)__shfl(my0, bl + j + 1) * 32 + l];
        f16x4 v2 = f4[(long long)__shfl(my0, bl + j + 2) * 32 + l];
        f16x4 v3 = f4[(long long)__shfl(my0, bl + j + 3) * 32 + l];
        f16x4 v4 = f4[(long long)__shfl(my0, bl + j + 4) * 32 + l];
        f16x4 v5 = f4[(long long)__shfl(my0, bl + j + 5) * 32 + l];
        f16x4 v6 = f4[(long long)__shfl(my0, bl + j + 6) * 32 + l];
        f16x4 v7 = f4[(long long)__shfl(my0, bl + j + 7) * 32 + l];
        a0 += (((float)v0[0] + (float)v1[0]) + ((float)v2[0] + (float)v3[0]))
            + (((float)v4[0] + (float)v5[0]) + ((float)v6[0] + (float)v7[0]));
        a1 += (((float)v0[1] + (float)v1[1]) + ((float)v2[1] + (float)v3[1]))
            + (((float)v4[1] + (float)v5[1]) + ((float)v6[1] + (float)v7[1]));
        a2 += (((float)v0[2] + (float)v1[2]) + ((float)v2[2] + (float)v3[2]))
            + (((float)v4[2] + (float)v5[2]) + ((float)v6[2] + (float)v7[2]));
        a3 += (((float)v0[3] + (float)v1[3]) + ((float)v2[3] + (float)v3[3]))
            + (((float)v4[3] + (float)v5[3]) + ((float)v6[3] + (float)v7[3]));
    }
    for (; j < lim0; j++) {
        f16x4 v = f4[(long long)__shfl(my0, bl + j) * 32 + l];
        a0 += (float)v[0]; a1 += (float)v[1]; a2 += (float)v[2]; a3 += (float)v[3];
    }
    for (; j + 8 <= n_it; j += 8) {
        f16x4 v0 = f4[(long long)__shfl(my1, bl + j - 32 + 0) * 32 + l];
        f16x4 v1 = f4[(long long)__shfl(my1, bl + j - 32 + 1) * 32 + l];
        f16x4 v2 = f4[(long long)__shfl(my1, bl + j - 32 + 2) * 32 + l];
        f16x4 v3 = f4[(long long)__shfl(my1, bl + j - 32 + 3) * 32 + l];
        f16x4 v4 = f4[(long long)__shfl(my1, bl + j - 32 + 4) * 32 + l];
        f16x4 v5 = f4[(long long)__shfl(my1, bl + j - 32 + 5) * 32 + l];
        f16x4 v6 = f4[(long long)__shfl(my1, bl + j - 32 + 6) * 32 + l];
        f16x4 v7 = f4[(long long)__shfl(my1, bl + j - 32 + 7) * 32 + l];
        a0 += (((float)v0[0] + (float)v1[0]) + ((float)v2[0] + (float)v3[0]))
            + (((float)v4[0] + (float)v5[0]) + ((float)v6[0] + (float)v7[0]));
        a1 += (((float)v0[1] + (float)v1[1]) + ((float)v2[1] + (float)v3[1]))
            + (((float)v4[1] + (float)v5[1]) + ((float)v6[1] + (float)v7[1]));
        a2 += (((float)v0[2] + (float)v1[2]) + ((float)v2[2] + (float)v3[2]))
            + (((float)v4[2] + (float)v5[2]) + ((float)v6[2] + (float)v7[2]));
        a3 += (((float)v0[3] + (float)v1[3]) + ((float)v2[3] + (float)v3[3]))
            + (((float)v4[3] + (float)v5[3]) + ((float)v6[3] + (float)v7[3]));
    }
    for (; j < n_it; j++) {
        f16x4 v = f4[(long long)__shfl(my1, bl + j - 32) * 32 + l];
        a0 += (float)v[0]; a1 += (float)v[1]; a2 += (float)v[2]; a3 += (float)v[3];
    }
    float inv = 1.f / fmaxf((float)deg, 1.f);
    f16x4 r;
    r[0] = (f16)(a0 * inv); r[1] = (f16)(a1 * inv);
    r[2] = (f16)(a2 * inv); r[3] = (f16)(a3 * inv);
    ((f16x4*)outb)[(long long)node * 32 + l] = r;
}

// ---------------------------------------------------------------------------
// Fused layer-1 + layer-2 pre-transform (R13-proven):
// Stage 1: h1 = relu(bn1(mean@W1l^T+b1+x@W1r^T)) -> per-wave LDS tile
// Stage 2: y2 = [h1@W2l^T | h1@W2r^T] -> global (h1 never hits HBM).
// ---------------------------------------------------------------------------
__global__ __launch_bounds__(256) void sage1_y2_kernel(
    const f16* __restrict__ Am, const f16* __restrict__ Ax,
    const f16* __restrict__ W1,
    const float* __restrict__ bias, const float* __restrict__ gamma,
    const float* __restrict__ beta, const float* __restrict__ bmean,
    const float* __restrict__ bvar,
    const f16* __restrict__ W2cat,  // [128][128]
    f16* __restrict__ y2) {
    __shared__ f16 ldsA[4][32][136];

    int tid  = threadIdx.x;
    int wave = tid >> 6;
    int lane = tid & 63;
    int m_base = blockIdx.x * 128 + wave * 32;
    int lrow = lane & 15;
    int lchunk = lane >> 4;

    f32x4 acc[2][8] = {};

#pragma unroll
    for (int phase = 0; phase < 2; phase++) {
        const f16* A = phase ? Ax : Am;
        const f16* Wp = W1 + phase * 128;
        f16x8 afrag[4][2];
#pragma unroll
        for (int kc = 0; kc < 4; kc++)
#pragma unroll
            for (int mf = 0; mf < 2; mf++) {
                int row = m_base + mf * 16 + lrow;
                row = row < N_NODES ? row : N_NODES - 1;
                afrag[kc][mf] = *(const f16x8*)(A + (long long)row * 128 + kc * 32 + lchunk * 8);
            }
#pragma unroll
        for (int nf = 0; nf < 8; nf++)
#pragma unroll
            for (int kc = 0; kc < 4; kc++) {
                f16x8 b = *(const f16x8*)(Wp + (long long)(nf * 16 + lrow) * 256
                                          + kc * 32 + lchunk * 8);
                acc[0][nf] = __builtin_amdgcn_mfma_f32_16x16x32_f16(afrag[kc][0], b, acc[0][nf], 0, 0, 0);
                acc[1][nf] = __builtin_amdgcn_mfma_f32_16x16x32_f16(afrag[kc][1], b, acc[1][nf], 0, 0, 0);
            }
    }

    // BN1 + ReLU -> per-wave LDS tile
#pragma unroll
    for (int nf = 0; nf < 8; nf++) {
        int n = nf * 16 + lrow;
        float mul = gamma[n] * rsqrtf(bvar[n] + 1e-5f);
        float add = (bias[n] - bmean[n]) * mul + beta[n];
#pragma unroll
        for (int mf = 0; mf < 2; mf++)
#pragma unroll
            for (int r = 0; r < 4; r++) {
                int rloc = mf * 16 + lchunk * 4 + r;
                ldsA[wave][rloc][n] = (f16)fmaxf(fmaf(acc[mf][nf][r], mul, add), 0.f);
            }
    }

    // Stage 2: y2 = h1_tile @ W2cat^T (K=128)
#pragma unroll
    for (int nf2 = 0; nf2 < 8; nf2++) {
        f32x4 acc2[2] = {};
#pragma unroll
        for (int kc = 0; kc < 4; kc++) {
            f16x8 b2 = *(const f16x8*)(W2cat + (long long)(nf2 * 16 + lrow) * 128
                                       + kc * 32 + lchunk * 8);
            f16x8 a0 = *(const f16x8*)&ldsA[wave][lrow][kc * 32 + lchunk * 8];
            f16x8 a1 = *(const f16x8*)&ldsA[wave][16 + lrow][kc * 32 + lchunk * 8];
            acc2[0] = __builtin_amdgcn_mfma_f32_16x16x32_f16(a0, b2, acc2[0], 0, 0, 0);
            acc2[1] = __builtin_amdgcn_mfma_f32_16x16x32_f16(a1, b2, acc2[1], 0, 0, 0);
        }
        int n = nf2 * 16 + lrow;
#pragma unroll
        for (int mf = 0; mf < 2; mf++)
#pragma unroll
            for (int r = 0; r < 4; r++) {
                int m = m_base + mf * 16 + lchunk * 4 + r;
                if (m < N_NODES) y2[(long long)m * 128 + n] = (f16)acc2[mf][r];
            }
    }
}

// ---------------------------------------------------------------------------
// Fused layer-2 aggregation + BN2 + ReLU + head. 16 nodes/block, 3125 blocks
// (same geometry as the proven agg_half — no grid shrink). Each 16-lane group
// finishes its node: gather-mean y2l, add y2r, BN2+ReLU in f32, then 10
// logits via 4 FMA + 4 shfl_xor reduce per class. No LDS, no syncthreads.
// ---------------------------------------------------------------------------
__global__ void agg2_head_kernel(const f16* __restrict__ y2,
                                 const int* __restrict__ cnt,
                                 const unsigned short* __restrict__ bucket,
                                 const float* __restrict__ b2,
                                 const float* __restrict__ gamma,
                                 const float* __restrict__ beta,
                                 const float* __restrict__ bmean,
                                 const float* __restrict__ bvar,
                                 const float* __restrict__ hw,
                                 const float* __restrict__ hb,
                                 float* __restrict__ outp) {
    int node = blockIdx.x * 16 + (threadIdx.x >> 4);
    int l  = threadIdx.x & 15;
    int bl = threadIdx.x & 48;
    int deg = cnt[node];
    int n_it = deg < CAP ? deg : CAP;
    const unsigned short* b = bucket + (long long)node * CAP;
    int my0 = (l < n_it)      ? (int)b[l]      : 0;
    int my1 = (16 + l < n_it) ? (int)b[16 + l] : 0;
    int my2 = (32 + l < n_it) ? (int)b[32 + l] : 0;
    int my3 = (48 + l < n_it) ? (int)b[48 + l] : 0;
    const f16x4* f4 = (const f16x4*)y2;
    float a0 = 0.f, a1 = 0.f, a2 = 0.f, a3 = 0.f;
    int j = 0;

#define AGG_SEC(MYREG, BASE)                                                     \
    {                                                                            \
        int lim = n_it < (BASE + 16) ? n_it : (BASE + 16);                       \
        for (; j + 8 <= lim; j += 8) {                                           \
            f16x4 v0 = f4[(long long)__shfl(MYREG, bl + j - BASE + 0) * 32 + l]; \
            f16x4 v1 = f4[(long long)__shfl(MYREG, bl + j - BASE + 1) * 32 + l]; \
            f16x4 v2 = f4[(long long)__shfl(MYREG, bl + j - BASE + 2) * 32 + l]; \
            f16x4 v3 = f4[(long long)__shfl(MYREG, bl + j - BASE + 3) * 32 + l]; \
            f16x4 v4 = f4[(long long)__shfl(MYREG, bl + j - BASE + 4) * 32 + l]; \
            f16x4 v5 = f4[(long long)__shfl(MYREG, bl + j - BASE + 5) * 32 + l]; \
            f16x4 v6 = f4[(long long)__shfl(MYREG, bl + j - BASE + 6) * 32 + l]; \
            f16x4 v7 = f4[(long long)__shfl(MYREG, bl + j - BASE + 7) * 32 + l]; \
            a0 += (((float)v0[0] + (float)v1[0]) + ((float)v2[0] + (float)v3[0]))\
                + (((float)v4[0] + (float)v5[0]) + ((float)v6[0] + (float)v7[0]));\
            a1 += (((float)v0[1] + (float)v1[1]) + ((float)v2[1] + (float)v3[1]))\
                + (((float)v4[1] + (float)v5[1]) + ((float)v6[1] + (float)v7[1]));\
            a2 += (((float)v0[2] + (float)v1[2]) + ((float)v2[2] + (float)v3[2]))\
                + (((float)v4[2] + (float)v5[2]) + ((float)v6[2] + (float)v7[2]));\
            a3 += (((float)v0[3] + (float)v1[3]) + ((float)v2[3] + (float)v3[3]))\
                + (((float)v4[3] + (float)v5[3]) + ((float)v6[3] + (float)v7[3]));\
        }                                                                        \
        for (; j < lim; j++) {                                                   \
            f16x4 v = f4[(long long)__shfl(MYREG, bl + j - BASE) * 32 + l];      \
            a0 += (float)v[0]; a1 += (float)v[1];                                \
            a2 += (float)v[2]; a3 += (float)v[3];                                \
        }                                                                        \
    }

    AGG_SEC(my0, 0)
    AGG_SEC(my1, 16)
    AGG_SEC(my2, 32)
    AGG_SEC(my3, 48)
#undef AGG_SEC

    // BN2 + ReLU in f32 (channels 4l..4l+3 of this node)
    float inv = 1.f / fmaxf((float)deg, 1.f);
    f16x4 yr = f4[(long long)node * 32 + 16 + l];   // y2r quad
    float h[4];
#pragma unroll
    for (int i = 0; i < 4; i++) {
        int n = l * 4 + i;
        float mul = gamma[n] * rsqrtf(bvar[n] + 1e-5f);
        float add = (b2[n] - bmean[n]) * mul + beta[n];
        float a = (i == 0 ? a0 : i == 1 ? a1 : i == 2 ? a2 : a3);
        h[i] = fmaxf(fmaf(a * inv + (float)yr[i], mul, add), 0.f);
    }

    // head: 10 logits, 16-lane group reduce per class
#pragma unroll
    for (int c = 0; c < N_CLASSES; c++) {
        const float* w = hw + c * 64 + l * 4;
        float p = h[0] * w[0] + h[1] * w[1] + h[2] * w[2] + h[3] * w[3];
        p += __shfl_xor(p, 8);
        p += __shfl_xor(p, 4);
        p += __shfl_xor(p, 2);
        p += __shfl_xor(p, 1);
        if (l == c) outp[(long long)node * N_CLASSES + c] = p + hb[c];
    }
}

// ---------------------------------------------------------------------------
extern "C" void kernel_launch(void* const* d_in, const int* in_sizes, int n_in,
                              void* d_out, int out_size, void* d_ws, size_t ws_size,
                              hipStream_t stream) {
    const float* x      = (const float*)d_in[0];
    const int*   ei     = (const int*)d_in[1];
    const float* w1l    = (const float*)d_in[2];
    const float* b1l    = (const float*)d_in[3];
    const float* w1r    = (const float*)d_in[4];
    const float* bn1_g  = (const float*)d_in[5];
    const float* bn1_b  = (const float*)d_in[6];
    const float* bn1_m  = (const float*)d_in[7];
    const float* bn1_v  = (const float*)d_in[8];
    const float* w2l    = (const float*)d_in[9];
    const float* b2l    = (const float*)d_in[10];
    const float* w2r    = (const float*)d_in[11];
    const float* bn2_g  = (const float*)d_in[12];
    const float* bn2_b  = (const float*)d_in[13];
    const float* bn2_m  = (const float*)d_in[14];
    const float* bn2_v  = (const float*)d_in[15];
    const float* head_w = (const float*)d_in[16];
    const float* head_b = (const float*)d_in[17];
    float* out = (float*)d_out;

    const int* src  = ei;
    const int* dstv = ei + N_EDGES;

    // workspace layout
    char* ws = (char*)d_ws;
    size_t off = 0;
    int* cnt               = (int*)(ws + off); off += ((size_t)N_NODES * 4 + 511) & ~511ull;
    unsigned short* bucket = (unsigned short*)(ws + off); off += (size_t)N_NODES * CAP * 2;
    f16* xh     = (f16*)(ws + off); off += (size_t)N_NODES * 128 * 2;
    f16* meanb  = (f16*)(ws + off); off += (size_t)N_NODES * 128 * 2;
    f16* y2     = (f16*)(ws + off); off += (size_t)N_NODES * 128 * 2;
    f16* W1     = (f16*)(ws + off); off += (size_t)128 * 256 * 2;
    f16* W2cat  = (f16*)(ws + off); off += (size_t)128 * 128 * 2;

    // --- fused bucket build + f16 conversion ---
    zero_cnt_kernel<<<(N_NODES / 4 + 255) / 256, 256, 0, stream>>>(cnt);
    build_fused_kernel<<<2 * EDGE_BLOCKS + 4, 256, 0, stream>>>(
        src, dstv, cnt, bucket, x, w1l, w1r, w2l, w2r, xh, W1, W2cat);

    // --- layer 1 + layer-2 pre-transform (fused) ---
    agg_mean_f16_kernel<<<N_NODES / 8, 256, 0, stream>>>(xh, cnt, bucket, meanb);
    sage1_y2_kernel<<<(N_NODES + 127) / 128, 256, 0, stream>>>(
        meanb, xh, W1, b1l, bn1_g, bn1_b, bn1_m, bn1_v, W2cat, y2);

    // --- layer-2 aggregate + BN2 + ReLU + head (fused, same grid as agg_half) ---
    agg2_head_kernel<<<N_NODES / 16, 256, 0, stream>>>(
        y2, cnt, bucket, b2l, bn2_g, bn2_b, bn2_m, bn2_v, head_w, head_b, out);
}